// Round 3
// baseline (27865.793 us; speedup 1.0000x reference)
//
#include <hip/hip_runtime.h>
#include <hip/hip_cooperative_groups.h>
#include <math.h>

namespace cg = cooperative_groups;

// Problem constants
#define NB   32
#define NT   300
#define NE   1024
#define NH   512
#define NA   256
#define NCC  10
#define NKW  201
#define NV   10000
#define NEMB 512
#define NAO  512
#define NTD  80
#define SCL  2.0f

__device__ __forceinline__ float sigf(float x){ return 1.f/(1.f+expf(-x)); }
__device__ __forceinline__ float dot4(float4 a, float4 b){
    return a.x*b.x + a.y*b.y + a.z*b.z + a.w*b.w;
}

union SmAll {
    struct { float As[32][68], Bs[32][68]; } pre;                       // 17.4 KB
    struct { float xk[32][132]; float gsum[8][32]; } gates;             // 17.9 KB
    struct { float dt[256], wh[240], ck[2016], wt[2560], wg[256],
             cv[384], esp[38][4]; } esc;                                // 23.4 KB
    struct { float es[304], wsm[304], red[512]; } ctxp;                 // 4.5 KB
    struct { float y[32][132]; } lg;                                    // 16.9 KB
    struct { float rv[512]; int ri[512]; } fin;                         // 4 KB
};

__global__ __launch_bounds__(512, 2) void mega(
    const float* __restrict__ enc_pad, const int* __restrict__ enc_len,
    const float* __restrict__ embedding,
    const float* __restrict__ W_ih, const float* __restrict__ b_ih,
    const float* __restrict__ W_hh, const float* __restrict__ b_hh,
    const float* __restrict__ W_enc, const float* __restrict__ b_enc,
    const float* __restrict__ W_dec, const float* __restrict__ W_att,
    const float* __restrict__ conv_k, const float* __restrict__ W_g,
    const float* __restrict__ W_o, const float* __restrict__ b_o,
    const float* __restrict__ W_out, const float* __restrict__ b_out,
    float* __restrict__ out_logits, float* __restrict__ out_ylp,
    float* __restrict__ out_preds, float* __restrict__ out_ws,
    float* __restrict__ pre_enc, float* __restrict__ zbuf,
    float* __restrict__ dec_c, float* __restrict__ cvec,
    float* __restrict__ ebuf, float* __restrict__ wbuf,
    float* __restrict__ ctx, int* __restrict__ prev)
{
    cg::grid_group gg = cg::this_grid();
    __shared__ SmAll sm;
    const int blk = blockIdx.x;     // 0..255
    const int tid = threadIdx.x;    // 0..511

    // ================= INIT: state + pre_enc GEMM =================
    {
        const int idx = blk*512 + tid;
        if (idx < NB*NH)  { zbuf[idx]=0.f; dec_c[idx]=0.f; cvec[idx]=0.f; }
        if (idx < NB*NT)  { const int b=idx/NT, t=idx%NT; const int len=enc_len[b];
                            wbuf[idx] = (t<len)? 1.f/(float)len : 0.f; }
        if (idx < NB)       prev[idx] = 1;   // BOS

        // pre_enc = enc_pad @ W_enc^T + b_enc : 600 tiles of 64x64, K=1024
        const int r  = tid>>3, kg = (tid&7)*4;
        const int ty = tid>>4, tx = tid&15;
        for (int tile = blk; tile < 600; tile += 256) {
            const int m0 = (tile>>2)*64, n0 = (tile&3)*64;
            float acc[2][4] = {};
            for (int k0 = 0; k0 < 1024; k0 += 32) {
                const float4 av = *(const float4*)(enc_pad + (size_t)(m0+r)*1024 + k0+kg);
                const float4 bv = *(const float4*)(W_enc  + (size_t)(n0+r)*1024 + k0+kg);
                __syncthreads();
                sm.pre.As[kg+0][r]=av.x; sm.pre.As[kg+1][r]=av.y;
                sm.pre.As[kg+2][r]=av.z; sm.pre.As[kg+3][r]=av.w;
                sm.pre.Bs[kg+0][r]=bv.x; sm.pre.Bs[kg+1][r]=bv.y;
                sm.pre.Bs[kg+2][r]=bv.z; sm.pre.Bs[kg+3][r]=bv.w;
                __syncthreads();
                #pragma unroll
                for (int kk = 0; kk < 32; ++kk) {
                    const float a0 = sm.pre.As[kk][ty*2];
                    const float a1 = sm.pre.As[kk][ty*2+1];
                    const float4 bb = *(const float4*)&sm.pre.Bs[kk][tx*4];
                    acc[0][0]+=a0*bb.x; acc[0][1]+=a0*bb.y; acc[0][2]+=a0*bb.z; acc[0][3]+=a0*bb.w;
                    acc[1][0]+=a1*bb.x; acc[1][1]+=a1*bb.y; acc[1][2]+=a1*bb.z; acc[1][3]+=a1*bb.w;
                }
            }
            #pragma unroll
            for (int i2 = 0; i2 < 2; ++i2) {
                const int mm = m0 + ty*2 + i2;
                #pragma unroll
                for (int j = 0; j < 4; ++j)
                    pre_enc[(size_t)mm*NA + n0 + tx*4 + j] = acc[i2][j] + b_enc[n0+tx*4+j];
            }
            __syncthreads();
        }
    }
    gg.sync();

    for (int step = 0; step < NTD; ++step) {
        // ============ P1: gates (x@[Wih|Whh]^T) + LSTM cell ============
        // block -> h-pair {2*blk, 2*blk+1}; 8 gate-rows x 32 b, K=1536
        {
            const int r8 = tid>>6;                 // 0..7: gate g=r8&3, hsub=r8>>2
            const int g = r8&3, hsub = r8>>2;
            const int row = g*512 + blk*2 + hsub;
            const int b2 = tid&63, b = b2>>1, kh = b2&1;
            const int sb = tid>>4, sk = (tid&15)*8;
            const int pv = prev[sb];
            float acc = 0.f;
            for (int ck = 0; ck < 12; ++ck) {
                const int gk = ck*128 + sk;
                float4 v0, v1;
                if (ck < 4)      { const float4* p=(const float4*)(embedding + (size_t)pv*NEMB + gk); v0=p[0]; v1=p[1]; }
                else if (ck < 8) { const float4* p=(const float4*)(cvec + sb*NAO + (gk-512));         v0=p[0]; v1=p[1]; }
                else             { const float4* p=(const float4*)(zbuf + sb*NH + (gk-1024));        v0=p[0]; v1=p[1]; }
                __syncthreads();
                *(float4*)&sm.gates.xk[sb][sk]   = v0;
                *(float4*)&sm.gates.xk[sb][sk+4] = v1;
                __syncthreads();
                const float* wrow = (ck < 8) ? (W_ih + (size_t)row*1024 + ck*128)
                                             : (W_hh + (size_t)row*512  + (ck-8)*128);
                const float* xr = &sm.gates.xk[b][kh*64];
                const float* wr = wrow + kh*64;
                #pragma unroll
                for (int c = 0; c < 16; ++c)
                    acc += dot4(*(const float4*)(xr + c*4), *(const float4*)(wr + c*4));
            }
            acc += __shfl_xor(acc, 1, 64);
            if ((b2 & 1) == 0) sm.gates.gsum[r8][b] = acc;
            __syncthreads();
            if (tid < 64) {
                const int hs = tid>>5, bb = tid&31;
                const int h = blk*2 + hs;
                const float gi = sm.gates.gsum[hs*4+0][bb] + b_ih[0*512+h] + b_hh[0*512+h];
                const float gf = sm.gates.gsum[hs*4+1][bb] + b_ih[1*512+h] + b_hh[1*512+h];
                const float gc = sm.gates.gsum[hs*4+2][bb] + b_ih[2*512+h] + b_hh[2*512+h];
                const float go = sm.gates.gsum[hs*4+3][bb] + b_ih[3*512+h] + b_hh[3*512+h];
                const int idx = bb*NH + h;
                const float cn = sigf(gf)*dec_c[idx] + sigf(gi)*tanhf(gc);
                dec_c[idx] = cn;
                zbuf[idx]  = sigf(go)*tanhf(cn);
            }
        }
        gg.sync();

        // ============ P3: dect (redundant per block) + conv + escore ============
        // block -> (b = blk>>3, t-chunk of 38)
        {
            const int b = blk>>3, tc = blk&7, t0 = tc*38;
            {   // dect: a = tid>>1, half-K per thread
                const int a = tid>>1, kh = tid&1;
                const float* zr = zbuf  + b*NH + kh*256;
                const float* wr = W_dec + (size_t)a*NH + kh*256;
                float acc = 0.f;
                #pragma unroll 8
                for (int c = 0; c < 64; ++c)
                    acc += dot4(*(const float4*)(zr + c*4), *(const float4*)(wr + c*4));
                acc += __shfl_xor(acc, 1, 64);
                if (kh == 0) sm.esc.dt[a] = acc;
            }
            for (int i = tid; i < 238; i += 512) {
                const int gt = t0 - 100 + i;
                sm.esc.wh[i] = (gt >= 0 && gt < NT) ? wbuf[b*NT + gt] : 0.f;
            }
            for (int i = tid; i < NCC*NKW; i += 512) sm.esc.ck[i] = conv_k[i];
            for (int i = tid; i < NA*NCC;  i += 512) sm.esc.wt[i] = W_att[i];
            if (tid < NA) sm.esc.wg[tid] = W_g[tid];
            __syncthreads();
            if (tid < 380) {
                const int tl = tid/10, ch = tid%10;
                float s = 0.f;
                const float* wp = &sm.esc.wh[tl];
                const float* kp = &sm.esc.ck[ch*NKW];
                for (int k = 0; k < NKW; ++k) s += wp[k]*kp[k];
                sm.esc.cv[tl*10 + ch] = s;
            }
            __syncthreads();
            const int a = tid&255, th = tid>>8;
            for (int tt = 0; tt < 19; ++tt) {
                const int tl = tt*2 + th;
                const int tg = t0 + tl;
                float val = 0.f;
                if (tg < NT) {
                    float attc = 0.f;
                    #pragma unroll
                    for (int ch = 0; ch < NCC; ++ch) attc += sm.esc.cv[tl*10+ch]*sm.esc.wt[a*10+ch];
                    val = tanhf(pre_enc[((size_t)b*NT + tg)*NA + a] + sm.esc.dt[a] + attc)*sm.esc.wg[a];
                }
                #pragma unroll
                for (int off = 32; off; off >>= 1) val += __shfl_xor(val, off, 64);
                if ((tid & 63) == 0) sm.esc.esp[tl][(tid>>6)&3] = val;
            }
            __syncthreads();
            if (tid < 38 && (t0 + tid) < NT)
                ebuf[b*NT + t0 + tid] = sm.esc.esp[tid][0]+sm.esc.esp[tid][1]
                                      + sm.esc.esp[tid][2]+sm.esc.esp[tid][3];
        }
        gg.sync();

        // ============ P4: softmax (redundant x8) + ctx ============
        // block -> (b = blk>>3, d-chunk of 128)
        {
            const int b = blk>>3, dc = blk&7, d0 = dc*128;
            for (int i = tid; i < NT; i += 512) sm.ctxp.es[i] = ebuf[b*NT+i];
            __syncthreads();
            float m = -3.4e38f;
            for (int i = tid; i < NT; i += 512) m = fmaxf(m, sm.ctxp.es[i]);
            sm.ctxp.red[tid] = m; __syncthreads();
            for (int o = 256; o; o >>= 1) {
                if (tid < o) sm.ctxp.red[tid] = fmaxf(sm.ctxp.red[tid], sm.ctxp.red[tid+o]);
                __syncthreads();
            }
            m = sm.ctxp.red[0]; __syncthreads();
            float ss = 0.f;
            for (int i = tid; i < NT; i += 512) ss += expf(SCL*(sm.ctxp.es[i]-m));
            sm.ctxp.red[tid] = ss; __syncthreads();
            for (int o = 256; o; o >>= 1) {
                if (tid < o) sm.ctxp.red[tid] += sm.ctxp.red[tid+o];
                __syncthreads();
            }
            const float inv = 1.f/sm.ctxp.red[0];
            for (int i = tid; i < NT; i += 512) {
                const float w = expf(SCL*(sm.ctxp.es[i]-m))*inv;
                sm.ctxp.wsm[i] = w;
                if (dc == 0) { wbuf[b*NT+i] = w; out_ws[((size_t)b*NTD+step)*NT+i] = w; }
            }
            __syncthreads();
            const int d = tid&127, tg4 = tid>>7;
            const float* ep = enc_pad + (size_t)b*NT*NE + d0 + d;
            float acc = 0.f;
            for (int t = tg4; t < NT; t += 4) acc += sm.ctxp.wsm[t]*ep[(size_t)t*NE];
            sm.ctxp.red[tg4*128 + d] = acc;
            __syncthreads();
            if (tid < 128)
                ctx[b*NE + d0 + tid] = sm.ctxp.red[tid] + sm.ctxp.red[128+tid]
                                     + sm.ctxp.red[256+tid] + sm.ctxp.red[384+tid];
        }
        gg.sync();

        // ============ P5: cvec = ctx @ W_o^T + b_o ============
        // block -> o-pair {2*blk, 2*blk+1}
        {
            const int os = tid>>8, o = blk*2 + os;
            const int b = (tid>>3)&31, ks = tid&7;
            const float* xr = ctx + b*NE + ks*128;
            const float* wr = W_o + (size_t)o*NE + ks*128;
            float acc = 0.f;
            #pragma unroll 8
            for (int c = 0; c < 32; ++c)
                acc += dot4(*(const float4*)(xr + c*4), *(const float4*)(wr + c*4));
            acc += __shfl_xor(acc, 1, 64);
            acc += __shfl_xor(acc, 2, 64);
            acc += __shfl_xor(acc, 4, 64);
            if (ks == 0) cvec[b*NAO + o] = acc + b_o[o];
        }
        gg.sync();

        // ============ P6: logits = [z|cvec] @ W_out^T + b_out -> d_out ============
        // block -> 40 v-rows; thread (b = tid&31, vs = tid>>5) x up to 3 rows
        {
            const int v0 = blk*40;
            const int b = tid&31, vs = tid>>5;
            const int sb = tid>>4, sk = (tid&15)*8;
            const int v1i = v0+vs, v2i = v0+vs+16, v3i = v0+vs+32;
            const int c1 = (v1i < NV)? v1i : NV-1;
            const int c2 = (v2i < NV)? v2i : NV-1;
            const int c3 = (v3i < NV)? v3i : NV-1;
            float a0=0.f, a1=0.f, a2=0.f;
            for (int ck = 0; ck < 8; ++ck) {
                const int gk = ck*128 + sk;
                float4 y0, y1;
                if (ck < 4) { const float4* p=(const float4*)(zbuf + sb*NH  + gk);       y0=p[0]; y1=p[1]; }
                else        { const float4* p=(const float4*)(cvec + sb*NAO + (gk-512)); y0=p[0]; y1=p[1]; }
                __syncthreads();
                *(float4*)&sm.lg.y[sb][sk]   = y0;
                *(float4*)&sm.lg.y[sb][sk+4] = y1;
                __syncthreads();
                const float* w1 = W_out + (size_t)c1*1024 + ck*128;
                const float* w2 = W_out + (size_t)c2*1024 + ck*128;
                const float* w3 = W_out + (size_t)c3*1024 + ck*128;
                #pragma unroll
                for (int c = 0; c < 32; ++c) {
                    const float4 yv = *(const float4*)&sm.lg.y[b][c*4];
                    a0 += dot4(yv, *(const float4*)(w1 + c*4));
                    a1 += dot4(yv, *(const float4*)(w2 + c*4));
                    a2 += dot4(yv, *(const float4*)(w3 + c*4));
                }
            }
            float* dst = out_logits + ((size_t)b*NTD + step)*NV;
            if (v1i < NV)              dst[v1i] = a0 + b_out[v1i];
            if (vs+16 < 40 && v2i < NV) dst[v2i] = a1 + b_out[v2i];
            if (vs+32 < 40 && v3i < NV) dst[v3i] = a2 + b_out[v3i];
        }
        gg.sync();

        // ============ P7: argmax + logsumexp (32 blocks) ============
        if (blk < NB) {
            const int b = blk;
            const float* lgr = out_logits + ((size_t)b*NTD + step)*NV;
            float m = -3.4e38f; int mi = 0;
            for (int v = tid; v < NV; v += 512) {
                const float x = lgr[v];
                if (x > m) { m = x; mi = v; }
            }
            sm.fin.rv[tid] = m; sm.fin.ri[tid] = mi;
            __syncthreads();
            for (int o = 256; o; o >>= 1) {
                if (tid < o) {
                    const float xm = sm.fin.rv[tid+o]; const int xi = sm.fin.ri[tid+o];
                    if (xm > sm.fin.rv[tid] || (xm == sm.fin.rv[tid] && xi < sm.fin.ri[tid])) {
                        sm.fin.rv[tid] = xm; sm.fin.ri[tid] = xi;
                    }
                }
                __syncthreads();
            }
            m = sm.fin.rv[0]; mi = sm.fin.ri[0];
            __syncthreads();
            float ss = 0.f;
            for (int v = tid; v < NV; v += 512) ss += expf(lgr[v] - m);
            sm.fin.rv[tid] = ss; __syncthreads();
            for (int o = 256; o; o >>= 1) {
                if (tid < o) sm.fin.rv[tid] += sm.fin.rv[tid+o];
                __syncthreads();
            }
            if (tid == 0) {
                prev[b] = mi;
                out_preds[b*NTD + step] = (float)mi;
                out_ylp[b*NTD + step]   = -logf(sm.fin.rv[0]);
            }
        }
        gg.sync();
    }
}

// ---------------------------------------------------------------------------
extern "C" void kernel_launch(void* const* d_in, const int* in_sizes, int n_in,
                              void* d_out, int out_size, void* d_ws, size_t ws_size,
                              hipStream_t stream)
{
    const float* enc_pad   = (const float*)d_in[0];
    const int*   enc_len   = (const int*)d_in[1];
    const float* embedding = (const float*)d_in[2];
    const float* W_ih      = (const float*)d_in[3];
    const float* b_ih      = (const float*)d_in[4];
    const float* W_hh      = (const float*)d_in[5];
    const float* b_hh      = (const float*)d_in[6];
    const float* W_enc     = (const float*)d_in[7];
    const float* b_enc     = (const float*)d_in[8];
    const float* W_dec     = (const float*)d_in[9];
    const float* W_att     = (const float*)d_in[10];
    const float* conv_k    = (const float*)d_in[11];
    const float* W_g       = (const float*)d_in[12];
    const float* W_o       = (const float*)d_in[13];
    const float* b_o       = (const float*)d_in[14];
    const float* W_out     = (const float*)d_in[15];
    const float* b_out     = (const float*)d_in[16];

    float* out_logits = (float*)d_out;                        // [B,TD,V]
    float* out_ylp    = out_logits + (size_t)NB*NTD*NV;       // [B,TD]
    float* out_preds  = out_ylp + NB*NTD;                     // [B,TD]
    float* out_ws     = out_preds + NB*NTD;                   // [B,TD,T]

    float* f = (float*)d_ws;
    float* pre_enc = f;                                   // 9600*256
    float* zbuf    = pre_enc + (size_t)NB*NT*NA;          // 32*512
    float* dec_c   = zbuf + NB*NH;                        // 32*512
    float* cvec    = dec_c + NB*NH;                       // 32*512
    float* ebuf    = cvec + NB*NAO;                       // 32*300
    float* wbuf    = ebuf + NB*NT;                        // 32*300
    float* ctx     = wbuf + NB*NT;                        // 32*1024
    int*   prev    = (int*)(ctx + NB*NE);                 // 32

    void* args[] = {
        (void*)&enc_pad, (void*)&enc_len, (void*)&embedding,
        (void*)&W_ih, (void*)&b_ih, (void*)&W_hh, (void*)&b_hh,
        (void*)&W_enc, (void*)&b_enc, (void*)&W_dec, (void*)&W_att,
        (void*)&conv_k, (void*)&W_g, (void*)&W_o, (void*)&b_o,
        (void*)&W_out, (void*)&b_out,
        (void*)&out_logits, (void*)&out_ylp, (void*)&out_preds, (void*)&out_ws,
        (void*)&pre_enc, (void*)&zbuf, (void*)&dec_c, (void*)&cvec,
        (void*)&ebuf, (void*)&wbuf, (void*)&ctx, (void*)&prev
    };
    hipLaunchCooperativeKernel((const void*)mega, dim3(256), dim3(512),
                               args, 0, stream);
}